// Round 4
// baseline (1258.083 us; speedup 1.0000x reference)
//
#include <hip/hip_runtime.h>
#include <hip/hip_bf16.h>
#include <math.h>

typedef __bf16 bf16_t;
typedef __bf16 bf16x8 __attribute__((ext_vector_type(8)));
typedef __bf16 bf16x4 __attribute__((ext_vector_type(4)));
typedef float  f32x4  __attribute__((ext_vector_type(4)));

#define T_ 8
#define B_ 16
#define C_ 256
#define V_ 1024
#define H_ 8
#define D_ 32

#define MFMA __builtin_amdgcn_mfma_f32_16x16x32_bf16

// async global->LDS, 16 B per lane. LDS dest must be lane-linear (base + lane*16).
__device__ __forceinline__ void gload16(const bf16_t* g, bf16_t* l)
{
    __builtin_amdgcn_global_load_lds(
        (const __attribute__((address_space(1))) unsigned int*)(g),
        (__attribute__((address_space(3))) unsigned int*)(l), 16, 0, 0);
}

// ---------------------------------------------------------------------------
// Layouts (all OUR intermediates are K-chunked so GEMM staging is contiguous):
//   xsT : [t][b][kq8][v1024][k32]   elem = (((t*16+b)*8+kq)*1024 + v)*32 + k
//   qT  : [t][b][h8][v1024][e32]    same formula (h = c>>5, e = c&31)
//   y3T : [t][b][h8][v1024][e32]    same
//   Wsp : [mat][lvl3][kq8][o256][k32]  elem = ((lvl*8+kq)*8192 + o*32 + k) per mat
//   kc,vc : [t][b][c256][v1024] (c-major, unchanged; consumed by k_attn)
// ---------------------------------------------------------------------------

// ---------------------------------------------------------------------------
// Prep: split four f32 256x256 matrices into 3-level bf16 splits, K-chunked.
// ---------------------------------------------------------------------------
__global__ __launch_bounds__(256) void k0_split4(const float* __restrict__ W0,
                                                 const float* __restrict__ W1,
                                                 const float* __restrict__ W2,
                                                 const float* __restrict__ W3,
                                                 bf16_t* __restrict__ S)
{
    const int mat = blockIdx.x >> 6;
    const float* W = (mat == 0) ? W0 : (mat == 1) ? W1 : (mat == 2) ? W2 : W3;
    bf16_t* Sm = S + (size_t)mat * 3 * 65536;
    int f = ((blockIdx.x & 63) * 256 + threadIdx.x) * 4;
    int o = f >> 8, c = f & 255;
    int kq = c >> 5, kk = c & 31;          // 4 consecutive kk stay in one chunk
    float4 w = *(const float4*)(W + f);
    float wv[4] = {w.x, w.y, w.z, w.w};
    bf16x4 s0, s1, s2;
#pragma unroll
    for (int j = 0; j < 4; j++) {
        bf16_t a = (bf16_t)wv[j];
        float r1 = wv[j] - (float)a;
        bf16_t b = (bf16_t)r1;
        float r2 = r1 - (float)b;
        bf16_t c2 = (bf16_t)r2;
        s0[j] = a; s1[j] = b; s2[j] = c2;
    }
    size_t base = (size_t)kq * 8192 + o * 32 + kk;      // lvl stride = 65536
    *(bf16x4*)(Sm + base)          = s0;
    *(bf16x4*)(Sm + 65536 + base)  = s1;
    *(bf16x4*)(Sm + 131072 + base) = s2;
}

// ---------------------------------------------------------------------------
// Kernel 1: shortcut LIF (tau=2, vth=1, hard reset) + transpose to chunked xsT
// ---------------------------------------------------------------------------
__global__ __launch_bounds__(256) void k1_lif_tr(const float* __restrict__ x,
                                                 bf16_t* __restrict__ xsT)
{
    __shared__ bf16_t tile[64 * 72];
    const int v0 = blockIdx.x * 64, c0 = blockIdx.y * 64, b = blockIdx.z;
    const int tid = threadIdx.x;
    const int cc = tid >> 2, v16 = (tid & 3) * 16;
    const int vr = tid >> 2, c16 = (tid & 3) * 16;
    float mem[16];
#pragma unroll
    for (int j = 0; j < 16; j++) mem[j] = 0.0f;

    for (int t = 0; t < T_; t++) {
        const float* xp = x + (((size_t)(t * B_ + b) * C_ + (c0 + cc)) * V_ + v0 + v16);
        float xv[16];
#pragma unroll
        for (int q = 0; q < 4; q++) {
            float4 f = *(const float4*)(xp + q * 4);
            xv[q * 4 + 0] = f.x; xv[q * 4 + 1] = f.y;
            xv[q * 4 + 2] = f.z; xv[q * 4 + 3] = f.w;
        }
#pragma unroll
        for (int j = 0; j < 16; j++) {
            float m = mem[j];
            float d = xv[j] - m;
            m = m + d * 0.5f;
            float s = (m >= 1.0f) ? 1.0f : 0.0f;
            tile[(v16 + j) * 72 + cc] = (bf16_t)s;
            mem[j] = (s != 0.0f) ? 0.0f : m;
        }
        __syncthreads();
        int c_abs = c0 + c16;
        bf16_t* op = xsT + ((((size_t)(t * B_ + b) * 8) + (c_abs >> 5)) * 1024 + (v0 + vr)) * 32
                         + (c_abs & 31);
        *(bf16x8*)op       = *(const bf16x8*)&tile[vr * 72 + c16];
        *(bf16x8*)(op + 8) = *(const bf16x8*)&tile[vr * 72 + c16 + 8];
        __syncthreads();
    }
}

// ---------------------------------------------------------------------------
// Branch GEMM (1x1 conv, triple-bf16-split weights) + BN + LIF fused over T.
// Round 4: m97 structure — global_load_lds(16B) staging from K-chunked
// layouts into linear unpadded LDS [64][32]; 2-barrier loop; no staging
// VGPRs/ds_writes/VALU. 256 thr, LDS 45 KiB -> 3 blocks/CU.
// ORIENT=0: out[t,b,c,v] (kc/vc). ORIENT=1: operand-swapped MFMA, out = qT
// chunked [t][b][h][v][e]. VOUT=1: also emit out1 f32 [T,B,H,N,D] via LDS
// transpose per t (replaces separate k_vout kernel).
// ---------------------------------------------------------------------------
template <int ORIENT, int VOUT>
__global__ __launch_bounds__(256, 3) void k_branch(const bf16_t* __restrict__ Wsp, // per-mat base
                                                   const float* __restrict__ bnp,  // [4][256]
                                                   const bf16_t* __restrict__ xsT,
                                                   bf16_t* __restrict__ outp, float vth,
                                                   float* __restrict__ out1)
{
    __shared__ bf16_t Wl[3][2048];      // [lvl][o64 x k32] linear
    __shared__ bf16_t Xl[8][2048];      // [t][v64 x k32] linear
    __shared__ float bsc[64], bmn[64], bbt[64];
    const int v0 = blockIdx.x * 64, o0 = blockIdx.y * 64, b = blockIdx.z;
    const int tid = threadIdx.x;
    const int w = tid >> 6, l = tid & 63, lq = l >> 4, lr = l & 15;
    const int msub = (w >> 1) * 32, nsub = (w & 1) * 32;
    const int srow = tid >> 2, sc16 = (tid & 3) * 8;    // staging: row + 16B quarter

    if (tid < 64) {
        int o = o0 + tid;
        float g = bnp[o], be = bnp[C_ + o];
        float mn = bnp[2 * C_ + o], vr2 = bnp[3 * C_ + o];
        bsc[tid] = g * (1.0f / sqrtf(vr2 + 1e-5f));
        bmn[tid] = mn; bbt[tid] = be;
    }

    f32x4 acc[8][4];
#pragma unroll
    for (int t = 0; t < 8; t++)
#pragma unroll
        for (int i = 0; i < 4; i++) acc[t][i] = (f32x4){0.f, 0.f, 0.f, 0.f};

    for (int kq = 0; kq < 8; kq++) {
        __syncthreads();                 // all waves done reading LDS of kq-1
#pragma unroll
        for (int lvl = 0; lvl < 3; lvl++)
            gload16(&Wsp[(size_t)(lvl * 8 + kq) * 8192 + (o0 + srow) * 32 + sc16],
                    &Wl[lvl][tid * 8]);
#pragma unroll
        for (int tt = 0; tt < 8; tt++)
            gload16(&xsT[((((size_t)(tt * B_ + b) * 8) + kq) * 1024 + v0 + srow) * 32 + sc16],
                    &Xl[tt][tid * 8]);
        __syncthreads();                 // compiler drains vmcnt(0) here

        bf16x8 aw0[3], aw1[3];
#pragma unroll
        for (int lvl = 0; lvl < 3; lvl++) {
            aw0[lvl] = *(const bf16x8*)&Wl[lvl][(msub + lr) * 32 + lq * 8];
            aw1[lvl] = *(const bf16x8*)&Wl[lvl][(msub + 16 + lr) * 32 + lq * 8];
        }
#pragma unroll
        for (int t = 0; t < 8; t++) {
            bf16x8 b0 = *(const bf16x8*)&Xl[t][(nsub + lr) * 32 + lq * 8];
            bf16x8 b1 = *(const bf16x8*)&Xl[t][(nsub + 16 + lr) * 32 + lq * 8];
#pragma unroll
            for (int lvl = 0; lvl < 3; lvl++) {     // same chain order as before
                if (ORIENT == 0) {
                    acc[t][0] = MFMA(aw0[lvl], b0, acc[t][0], 0, 0, 0);
                    acc[t][1] = MFMA(aw0[lvl], b1, acc[t][1], 0, 0, 0);
                    acc[t][2] = MFMA(aw1[lvl], b0, acc[t][2], 0, 0, 0);
                    acc[t][3] = MFMA(aw1[lvl], b1, acc[t][3], 0, 0, 0);
                } else {
                    acc[t][0] = MFMA(b0, aw0[lvl], acc[t][0], 0, 0, 0);
                    acc[t][1] = MFMA(b1, aw0[lvl], acc[t][1], 0, 0, 0);
                    acc[t][2] = MFMA(b0, aw1[lvl], acc[t][2], 0, 0, 0);
                    acc[t][3] = MFMA(b1, aw1[lvl], acc[t][3], 0, 0, 0);
                }
            }
        }
    }

    // epilogue: BN + LIF recurrence over t + spike store (+ optional out1)
    bf16_t* tl = (bf16_t*)Xl;            // VOUT transpose buffer (64x66), aliases Xl
    if (VOUT) __syncthreads();
    float mem[4][4];
#pragma unroll
    for (int st = 0; st < 4; st++)
#pragma unroll
        for (int r = 0; r < 4; r++) mem[st][r] = 0.0f;
#pragma unroll
    for (int t = 0; t < 8; t++) {
#pragma unroll
        for (int st = 0; st < 4; st++) {
            int mi = st >> 1, ni = st & 1;
#pragma unroll
            for (int r = 0; r < 4; r++) {
                int m, n;
                if (ORIENT == 0) {       // A=W: m on lq*4+r; B=X: n on lr
                    m = msub + mi * 16 + lq * 4 + r;
                    n = nsub + ni * 16 + lr;
                } else {                 // A=X: n on lq*4+r; B=W: m on lr
                    m = msub + mi * 16 + lr;
                    n = nsub + ni * 16 + lq * 4 + r;
                }
                float y = (acc[t][st][r] - bmn[m]) * bsc[m] + bbt[m];
                float mm = mem[st][r];
                mm = mm + (y - mm) * 0.5f;
                float s = (mm >= vth) ? 1.0f : 0.0f;
                size_t idx;
                if (ORIENT == 0) {
                    idx = ((size_t)(t * B_ + b) * C_ + (o0 + m)) * V_ + (v0 + n);
                } else {
                    int o_abs = o0 + m;
                    idx = ((((size_t)(t * B_ + b) * 8) + (o_abs >> 5)) * 1024 + (v0 + n)) * 32
                        + (o_abs & 31);
                }
                outp[idx] = (bf16_t)s;
                mem[st][r] = (s != 0.0f) ? 0.0f : mm;
                if (VOUT) tl[n * 66 + m] = (bf16_t)s;
            }
        }
        if (VOUT) {
            __syncthreads();
            // out1[t,b,h,n,d] f32: thread -> (n = tid&63, 16-wide o chunk)
            int nn = tid & 63, ho = tid >> 6;
            int h = (o0 >> 5) + (ho >> 1), d16 = (ho & 1) * 16;
            float* op = out1 + ((size_t)((t * B_ + b) * H_ + h)) * (V_ * D_)
                             + (size_t)(v0 + nn) * D_ + d16;
#pragma unroll
            for (int q2 = 0; q2 < 4; q2++) {
                float4 o4;
                o4.x = (float)tl[nn * 66 + ho * 16 + q2 * 4 + 0];
                o4.y = (float)tl[nn * 66 + ho * 16 + q2 * 4 + 1];
                o4.z = (float)tl[nn * 66 + ho * 16 + q2 * 4 + 2];
                o4.w = (float)tl[nn * 66 + ho * 16 + q2 * 4 + 3];
                *(float4*)(op + q2 * 4) = o4;
            }
            __syncthreads();
        }
    }
}

// ---------------------------------------------------------------------------
// attn^T[e][d] = (1/N) * sum_{t in chunk, n} v[e,n] * k[d,n] (exact integers),
// stored as exact hi/lo bf16 split. 4 waves split the 64 s-steps, LDS reduce.
// ---------------------------------------------------------------------------
__global__ __launch_bounds__(256) void k_attn(const bf16_t* __restrict__ vc,
                                              const bf16_t* __restrict__ kc,
                                              bf16_t* __restrict__ ahi,
                                              bf16_t* __restrict__ alo)
{
    __shared__ float red[3][64][20];
    const int fid = blockIdx.x;                 // ((nc*16+b)*8+h)
    const int h = fid & 7, b = (fid >> 3) & 15, nc = fid >> 7;
    const int tid = threadIdx.x, w = tid >> 6, l = tid & 63, lq = l >> 4, lr = l & 15;
    f32x4 acc[4];
#pragma unroll
    for (int i = 0; i < 4; i++) acc[i] = (f32x4){0.f, 0.f, 0.f, 0.f};
    for (int ss = 0; ss < 16; ss++) {
        int s = w * 16 + ss;
        int t = nc * 2 + (s >> 5);
        int n0 = (s & 31) * 32;
        size_t rb = ((size_t)(t * B_ + b) * C_ + h * D_ + lr) * V_ + n0 + lq * 8;
        bf16x8 a0 = *(const bf16x8*)&vc[rb];
        bf16x8 a1 = *(const bf16x8*)&vc[rb + (size_t)16 * V_];
        bf16x8 b0 = *(const bf16x8*)&kc[rb];
        bf16x8 b1 = *(const bf16x8*)&kc[rb + (size_t)16 * V_];
        acc[0] = MFMA(a0, b0, acc[0], 0, 0, 0);
        acc[1] = MFMA(a0, b1, acc[1], 0, 0, 0);
        acc[2] = MFMA(a1, b0, acc[2], 0, 0, 0);
        acc[3] = MFMA(a1, b1, acc[3], 0, 0, 0);
    }
    if (w) {
#pragma unroll
        for (int st = 0; st < 4; st++)
            *(f32x4*)&red[w - 1][l][st * 4] = acc[st];
    }
    __syncthreads();
    if (w == 0) {
#pragma unroll
        for (int st = 0; st < 4; st++)
#pragma unroll
            for (int i = 0; i < 3; i++)
                acc[st] += *(const f32x4*)&red[i][l][st * 4];

        size_t ob = (size_t)fid * 1024;
#pragma unroll
        for (int st = 0; st < 4; st++) {
            int ei = st >> 1, di = st & 1;
#pragma unroll
            for (int r = 0; r < 4; r++) {
                int e = ei * 16 + lq * 4 + r;
                int d = di * 16 + lr;
                float val = acc[st][r] * (1.0f / 1024.0f);   // exact dyadic
                bf16_t hi = (bf16_t)val;
                float lo = val - (float)hi;                  // exact residual
                ahi[ob + e * 32 + d] = hi;
                alo[ob + e * 32 + d] = (bf16_t)lo;
            }
        }
    }
}

// ---------------------------------------------------------------------------
// y2 = q . attn (exact hi/lo double-MFMA), fused attn_lif (vth=0.5, exact)
// -> spikes y3T chunked [t][b][h][v][e]. qT reads are contiguous 1KiB/wave.
// ---------------------------------------------------------------------------
__global__ __launch_bounds__(256) void k_attn_out(const bf16_t* __restrict__ qT,
                                                  const bf16_t* __restrict__ ahi,
                                                  const bf16_t* __restrict__ alo,
                                                  bf16_t* __restrict__ y3T)
{
    const int tid = threadIdx.x, w = tid >> 6, l = tid & 63, lq = l >> 4, lr = l & 15;
    const int n0 = blockIdx.x * 64 + (w >> 1) * 32;
    const int h = blockIdx.y * 2 + (w & 1);
    const int b = blockIdx.z;
    float mem[4][4];
#pragma unroll
    for (int st = 0; st < 4; st++)
#pragma unroll
        for (int r = 0; r < 4; r++) mem[st][r] = 0.0f;

    for (int t = 0; t < T_; t++) {
        int nc = t >> 1;
        size_t qb = (((size_t)(t * B_ + b) * 8) + h) * 32768;
        bf16x8 a0 = *(const bf16x8*)&qT[qb + (n0 + lr) * 32 + lq * 8];
        bf16x8 a1 = *(const bf16x8*)&qT[qb + (n0 + 16 + lr) * 32 + lq * 8];
        size_t ab = ((size_t)(nc * B_ + b) * H_ + h) * 1024;
        bf16x8 bh0 = *(const bf16x8*)&ahi[ab + lr * 32 + lq * 8];
        bf16x8 bh1 = *(const bf16x8*)&ahi[ab + (16 + lr) * 32 + lq * 8];
        bf16x8 bl0 = *(const bf16x8*)&alo[ab + lr * 32 + lq * 8];
        bf16x8 bl1 = *(const bf16x8*)&alo[ab + (16 + lr) * 32 + lq * 8];
#pragma unroll
        for (int st = 0; st < 4; st++) {
            int mi = st >> 1, ni = st & 1;
            f32x4 z = (f32x4){0.f, 0.f, 0.f, 0.f};
            z = MFMA(mi ? a1 : a0, ni ? bh1 : bh0, z, 0, 0, 0);
            z = MFMA(mi ? a1 : a0, ni ? bl1 : bl0, z, 0, 0, 0);
#pragma unroll
            for (int r = 0; r < 4; r++) {
                int n = n0 + mi * 16 + lq * 4 + r;
                int e = ni * 16 + lr;
                float mm = mem[st][r];
                mm = mm + (z[r] - mm) * 0.5f;
                float s = (mm >= 0.5f) ? 1.0f : 0.0f;
                y3T[(((size_t)(t * B_ + b) * 8) + h) * 32768 + (size_t)n * 32 + e] = (bf16_t)s;
                mem[st][r] = (s != 0.0f) ? 0.0f : mm;
            }
        }
    }
}

// ---------------------------------------------------------------------------
// proj GEMM (triple split, m97-style gload_lds staging) + bias + BN + identity
// ---------------------------------------------------------------------------
__global__ __launch_bounds__(256, 3) void k_proj(const bf16_t* __restrict__ Wsp,
                                                 const float* __restrict__ pb,
                                                 const float* __restrict__ bnp,
                                                 const bf16_t* __restrict__ y3T,
                                                 const float* __restrict__ x,
                                                 float* __restrict__ out0)
{
    __shared__ bf16_t Wl[3][2048];
    __shared__ bf16_t Xl[8][2048];
    __shared__ float bsc[64], bmn[64], bbt[64], bbi[64];
    const int v0 = blockIdx.x * 64, o0 = blockIdx.y * 64, b = blockIdx.z;
    const int tid = threadIdx.x;
    const int w = tid >> 6, l = tid & 63, lq = l >> 4, lr = l & 15;
    const int msub = (w >> 1) * 32, nsub = (w & 1) * 32;
    const int srow = tid >> 2, sc16 = (tid & 3) * 8;

    if (tid < 64) {
        int o = o0 + tid;
        float g = bnp[o], be = bnp[C_ + o];
        float mn = bnp[2 * C_ + o], vr2 = bnp[3 * C_ + o];
        bsc[tid] = g * (1.0f / sqrtf(vr2 + 1e-5f));
        bmn[tid] = mn; bbt[tid] = be; bbi[tid] = pb[o];
    }

    f32x4 acc[8][4];
#pragma unroll
    for (int t = 0; t < 8; t++)
#pragma unroll
        for (int i = 0; i < 4; i++) acc[t][i] = (f32x4){0.f, 0.f, 0.f, 0.f};

    for (int kq = 0; kq < 8; kq++) {
        __syncthreads();
#pragma unroll
        for (int lvl = 0; lvl < 3; lvl++)
            gload16(&Wsp[(size_t)(lvl * 8 + kq) * 8192 + (o0 + srow) * 32 + sc16],
                    &Wl[lvl][tid * 8]);
#pragma unroll
        for (int tt = 0; tt < 8; tt++)
            gload16(&y3T[((((size_t)(tt * B_ + b) * 8) + kq) * 1024 + v0 + srow) * 32 + sc16],
                    &Xl[tt][tid * 8]);
        __syncthreads();

        bf16x8 aw0[3], aw1[3];
#pragma unroll
        for (int lvl = 0; lvl < 3; lvl++) {
            aw0[lvl] = *(const bf16x8*)&Wl[lvl][(msub + lr) * 32 + lq * 8];
            aw1[lvl] = *(const bf16x8*)&Wl[lvl][(msub + 16 + lr) * 32 + lq * 8];
        }
#pragma unroll
        for (int t = 0; t < 8; t++) {
            bf16x8 b0 = *(const bf16x8*)&Xl[t][(nsub + lr) * 32 + lq * 8];
            bf16x8 b1 = *(const bf16x8*)&Xl[t][(nsub + 16 + lr) * 32 + lq * 8];
#pragma unroll
            for (int lvl = 0; lvl < 3; lvl++) {
                acc[t][0] = MFMA(aw0[lvl], b0, acc[t][0], 0, 0, 0);
                acc[t][1] = MFMA(aw0[lvl], b1, acc[t][1], 0, 0, 0);
                acc[t][2] = MFMA(aw1[lvl], b0, acc[t][2], 0, 0, 0);
                acc[t][3] = MFMA(aw1[lvl], b1, acc[t][3], 0, 0, 0);
            }
        }
    }

#pragma unroll
    for (int t = 0; t < 8; t++) {
#pragma unroll
        for (int st = 0; st < 4; st++) {
            int mi = st >> 1, ni = st & 1;
#pragma unroll
            for (int r = 0; r < 4; r++) {
                int m = msub + mi * 16 + lq * 4 + r;
                int n = nsub + ni * 16 + lr;
                size_t idx = ((size_t)(t * B_ + b) * C_ + (o0 + m)) * V_ + (v0 + n);
                float y = acc[t][st][r] + bbi[m];
                y = (y - bmn[m]) * bsc[m] + bbt[m];
                y += x[idx];
                out0[idx] = y;
            }
        }
    }
}

// ---------------------------------------------------------------------------
extern "C" void kernel_launch(void* const* d_in, const int* in_sizes, int n_in,
                              void* d_out, int out_size, void* d_ws, size_t ws_size,
                              hipStream_t stream)
{
    const float* x    = (const float*)d_in[0];
    const float* q_w  = (const float*)d_in[1];
    const float* k_w  = (const float*)d_in[2];
    const float* v_w  = (const float*)d_in[3];
    const float* pw   = (const float*)d_in[4];
    const float* pb   = (const float*)d_in[5];
    const float* bn_q = (const float*)d_in[6];
    const float* bn_k = (const float*)d_in[7];
    const float* bn_v = (const float*)d_in[8];
    const float* bn_p = (const float*)d_in[9];

    char* ws = (char*)d_ws;
    bf16_t* xsT  = (bf16_t*)(ws);                                 // 64 MiB (reused as y3T)
    bf16_t* vc   = (bf16_t*)(ws + ((size_t)64 << 20));            // 64 MiB
    bf16_t* ahi  = (bf16_t*)(ws + ((size_t)128 << 20));           // 1 MiB
    bf16_t* alo  = (bf16_t*)(ws + ((size_t)129 << 20));           // 1 MiB
    bf16_t* wspq = (bf16_t*)(ws + ((size_t)130 << 20));           // 4 x 384 KiB
    bf16_t* wspk = wspq + 3 * 65536;
    bf16_t* wspv = wspk + 3 * 65536;
    bf16_t* wspp = wspv + 3 * 65536;
    bf16_t* y3T  = xsT;                                           // reuse after v-branch

    float* outf = (float*)d_out;
    float* out1 = outf + (size_t)33554432;                        // [T,B,H,N,D] f32
    bf16_t* qT = (bf16_t*)d_out;                                  // scratch in out0 half
    bf16_t* kc = (bf16_t*)((char*)d_out + ((size_t)64 << 20));    // scratch in out0 half

    k0_split4   <<<dim3(256),       256, 0, stream>>>(q_w, k_w, v_w, pw, wspq);
    k1_lif_tr   <<<dim3(16, 4, 16), 256, 0, stream>>>(x, xsT);
    k_branch<1,0><<<dim3(16, 4, 16),256, 0, stream>>>(wspq, bn_q, xsT, qT, 1.0f, nullptr);
    k_branch<0,0><<<dim3(16, 4, 16),256, 0, stream>>>(wspk, bn_k, xsT, kc, 1.0f, nullptr);
    k_branch<0,1><<<dim3(16, 4, 16),256, 0, stream>>>(wspv, bn_v, xsT, vc, 1.0f, out1);
    k_attn      <<<dim3(512),       256, 0, stream>>>(vc, kc, ahi, alo);
    k_attn_out  <<<dim3(16, 4, 16), 256, 0, stream>>>(qT, ahi, alo, y3T);
    k_proj      <<<dim3(16, 4, 16), 256, 0, stream>>>(wspp, pb, bn_p, y3T, x, outf);
}

// Round 5
// 696.540 us; speedup vs baseline: 1.8062x; 1.8062x over previous
//
#include <hip/hip_runtime.h>
#include <hip/hip_bf16.h>
#include <math.h>

typedef __bf16 bf16_t;
typedef __bf16 bf16x8 __attribute__((ext_vector_type(8)));
typedef __bf16 bf16x4 __attribute__((ext_vector_type(4)));
typedef float  f32x4  __attribute__((ext_vector_type(4)));

#define T_ 8
#define B_ 16
#define C_ 256
#define V_ 1024
#define H_ 8
#define D_ 32

#define MFMA __builtin_amdgcn_mfma_f32_16x16x32_bf16

// ---------------------------------------------------------------------------
// Prep: split four f32 256x256 matrices into 3-level bf16 splits (one launch).
// Layout per mat: [lvl][256 o][256 c] (round-1 layout).
// ---------------------------------------------------------------------------
__global__ __launch_bounds__(256) void k0_split4(const float* __restrict__ W0,
                                                 const float* __restrict__ W1,
                                                 const float* __restrict__ W2,
                                                 const float* __restrict__ W3,
                                                 bf16_t* __restrict__ S)
{
    const int mat = blockIdx.x >> 6;
    const float* W = (mat == 0) ? W0 : (mat == 1) ? W1 : (mat == 2) ? W2 : W3;
    bf16_t* S0 = S + (size_t)mat * 3 * 65536;
    bf16_t* S1 = S0 + 65536;
    bf16_t* S2 = S0 + 131072;
    int i = ((blockIdx.x & 63) * 256 + threadIdx.x) * 4;
    float4 w = *(const float4*)(W + i);
    float wv[4] = {w.x, w.y, w.z, w.w};
    bf16x4 s0, s1, s2;
#pragma unroll
    for (int j = 0; j < 4; j++) {
        bf16_t a = (bf16_t)wv[j];
        float r1 = wv[j] - (float)a;
        bf16_t b = (bf16_t)r1;
        float r2 = r1 - (float)b;
        bf16_t c = (bf16_t)r2;
        s0[j] = a; s1[j] = b; s2[j] = c;
    }
    *(bf16x4*)(S0 + i) = s0;
    *(bf16x4*)(S1 + i) = s1;
    *(bf16x4*)(S2 + i) = s2;
}

// ---------------------------------------------------------------------------
// Kernel 1: shortcut LIF (tau=2, vth=1, hard reset) + transpose to [T,B,V,C]
// ---------------------------------------------------------------------------
__global__ __launch_bounds__(256) void k1_lif_tr(const float* __restrict__ x,
                                                 bf16_t* __restrict__ xsT)
{
    __shared__ bf16_t tile[64 * 72];
    const int v0 = blockIdx.x * 64, c0 = blockIdx.y * 64, b = blockIdx.z;
    const int tid = threadIdx.x;
    const int cc = tid >> 2, v16 = (tid & 3) * 16;
    const int vr = tid >> 2, c16 = (tid & 3) * 16;
    float mem[16];
#pragma unroll
    for (int j = 0; j < 16; j++) mem[j] = 0.0f;

    for (int t = 0; t < T_; t++) {
        const float* xp = x + (((size_t)(t * B_ + b) * C_ + (c0 + cc)) * V_ + v0 + v16);
        float xv[16];
#pragma unroll
        for (int q = 0; q < 4; q++) {
            float4 f = *(const float4*)(xp + q * 4);
            xv[q * 4 + 0] = f.x; xv[q * 4 + 1] = f.y;
            xv[q * 4 + 2] = f.z; xv[q * 4 + 3] = f.w;
        }
#pragma unroll
        for (int j = 0; j < 16; j++) {
            float m = mem[j];
            float d = xv[j] - m;
            m = m + d * 0.5f;
            float s = (m >= 1.0f) ? 1.0f : 0.0f;
            tile[(v16 + j) * 72 + cc] = (bf16_t)s;
            mem[j] = (s != 0.0f) ? 0.0f : m;
        }
        __syncthreads();
        bf16_t* op = xsT + (((size_t)(t * B_ + b) * V_ + (v0 + vr)) * C_ + c0 + c16);
        *(bf16x8*)op       = *(const bf16x8*)&tile[vr * 72 + c16];
        *(bf16x8*)(op + 8) = *(const bf16x8*)&tile[vr * 72 + c16 + 8];
        __syncthreads();
    }
}

// ---------------------------------------------------------------------------
// Branch GEMM (1x1 conv, triple-bf16-split weights) + BN + LIF fused over T.
// Round-1 body (reg-staged, 4 waves, padded LDS). Round-5 change: the
// epilogue routes spikes through a 64x64 LDS tile so global stores are
// vectorized bf16x8 with each 4-lane group covering a full 128B line —
// replaces 128 scalar 2B stores per thread (the serialized epilogue burst).
// ORIENT=0: out[t,b,o,v]. ORIENT=1: operand-swapped MFMA, out[t,b,v,o].
// ---------------------------------------------------------------------------
template <int ORIENT>
__global__ __launch_bounds__(256, 2) void k_branch(const bf16_t* __restrict__ Wsp, // [3][256][256]
                                                   const float* __restrict__ bnp,  // [4][256]
                                                   const bf16_t* __restrict__ xsT,
                                                   bf16_t* __restrict__ outp, float vth)
{
    __shared__ bf16_t Wl[3][64 * 40];   // stride 40: 2-way bank alias only (free)
    __shared__ bf16_t Xl[8][64 * 40];
    __shared__ float bsc[64], bmn[64], bbt[64];
    const int v0 = blockIdx.x * 64, o0 = blockIdx.y * 64, b = blockIdx.z;
    const int tid = threadIdx.x;
    const int w = tid >> 6, l = tid & 63, lq = l >> 4, lr = l & 15;
    const int msub = (w >> 1) * 32, nsub = (w & 1) * 32;

    if (tid < 64) {
        int o = o0 + tid;
        float g = bnp[o], be = bnp[C_ + o];
        float mn = bnp[2 * C_ + o], vr2 = bnp[3 * C_ + o];
        bsc[tid] = g * (1.0f / sqrtf(vr2 + 1e-5f));
        bmn[tid] = mn; bbt[tid] = be;
    }

    f32x4 acc[8][4];
#pragma unroll
    for (int t = 0; t < 8; t++)
#pragma unroll
        for (int i = 0; i < 4; i++) acc[t][i] = (f32x4){0.f, 0.f, 0.f, 0.f};

    for (int kq = 0; kq < 8; kq++) {
        __syncthreads();
#pragma unroll
        for (int i = 0; i < 3; i++) {               // stage W chunk: 3*64*32
            int ch = tid + i * 256;
            int lvl = ch >> 8, rem = ch & 255;
            int row = rem >> 2, col8 = (rem & 3) * 8;
            *(bf16x8*)&Wl[lvl][row * 40 + col8] =
                *(const bf16x8*)&Wsp[lvl * 65536 + (o0 + row) * 256 + kq * 32 + col8];
        }
#pragma unroll
        for (int i = 0; i < 8; i++) {               // stage X chunk: 8t*64v*32k
            int ch = tid + i * 256;
            int tt = ch >> 8, rem = ch & 255;
            int row = rem >> 2, col8 = (rem & 3) * 8;
            *(bf16x8*)&Xl[tt][row * 40 + col8] =
                *(const bf16x8*)&xsT[((size_t)(tt * B_ + b) * V_ + v0 + row) * C_ + kq * 32 + col8];
        }
        __syncthreads();

        bf16x8 aw0[3], aw1[3];
#pragma unroll
        for (int lvl = 0; lvl < 3; lvl++) {
            aw0[lvl] = *(const bf16x8*)&Wl[lvl][(msub + lr) * 40 + lq * 8];
            aw1[lvl] = *(const bf16x8*)&Wl[lvl][(msub + 16 + lr) * 40 + lq * 8];
        }
#pragma unroll
        for (int t = 0; t < 8; t++) {
            bf16x8 b0 = *(const bf16x8*)&Xl[t][(nsub + lr) * 40 + lq * 8];
            bf16x8 b1 = *(const bf16x8*)&Xl[t][(nsub + 16 + lr) * 40 + lq * 8];
#pragma unroll
            for (int lvl = 0; lvl < 3; lvl++) {     // same chain order as round 1
                if (ORIENT == 0) {
                    acc[t][0] = MFMA(aw0[lvl], b0, acc[t][0], 0, 0, 0);
                    acc[t][1] = MFMA(aw0[lvl], b1, acc[t][1], 0, 0, 0);
                    acc[t][2] = MFMA(aw1[lvl], b0, acc[t][2], 0, 0, 0);
                    acc[t][3] = MFMA(aw1[lvl], b1, acc[t][3], 0, 0, 0);
                } else {
                    acc[t][0] = MFMA(b0, aw0[lvl], acc[t][0], 0, 0, 0);
                    acc[t][1] = MFMA(b1, aw0[lvl], acc[t][1], 0, 0, 0);
                    acc[t][2] = MFMA(b0, aw1[lvl], acc[t][2], 0, 0, 0);
                    acc[t][3] = MFMA(b1, aw1[lvl], acc[t][3], 0, 0, 0);
                }
            }
        }
    }

    // epilogue: BN + LIF over t; spikes through LDS tile -> vectorized stores
    __syncthreads();                      // all waves done reading Xl (kq=7)
    bf16_t* tl = (bf16_t*)Xl;             // 64 x 72 bf16 tile, aliases Xl
    const int orow = tid >> 2, ocol = (tid & 3) * 16;
    float mem[4][4];
#pragma unroll
    for (int st = 0; st < 4; st++)
#pragma unroll
        for (int r = 0; r < 4; r++) mem[st][r] = 0.0f;
#pragma unroll
    for (int t = 0; t < 8; t++) {
#pragma unroll
        for (int st = 0; st < 4; st++) {
            int mi = st >> 1, ni = st & 1;
#pragma unroll
            for (int r = 0; r < 4; r++) {
                int m, n;
                if (ORIENT == 0) {        // A=W: m on lq*4+r; B=X: n on lr
                    m = msub + mi * 16 + lq * 4 + r;
                    n = nsub + ni * 16 + lr;
                } else {                  // A=X: n on lq*4+r; B=W: m on lr
                    m = msub + mi * 16 + lr;
                    n = nsub + ni * 16 + lq * 4 + r;
                }
                float y = (acc[t][st][r] - bmn[m]) * bsc[m] + bbt[m];
                float mm = mem[st][r];
                mm = mm + (y - mm) * 0.5f;
                float s = (mm >= vth) ? 1.0f : 0.0f;
                mem[st][r] = (s != 0.0f) ? 0.0f : mm;
                if (ORIENT == 0) tl[m * 72 + n] = (bf16_t)s;   // tile rows = o
                else             tl[n * 72 + m] = (bf16_t)s;   // tile rows = v
            }
        }
        __syncthreads();
        size_t rowbase;
        if (ORIENT == 0)
            rowbase = ((size_t)(t * B_ + b) * C_ + (o0 + orow)) * V_ + v0 + ocol;
        else
            rowbase = ((size_t)(t * B_ + b) * V_ + (v0 + orow)) * C_ + o0 + ocol;
        *(bf16x8*)&outp[rowbase]     = *(const bf16x8*)&tl[orow * 72 + ocol];
        *(bf16x8*)&outp[rowbase + 8] = *(const bf16x8*)&tl[orow * 72 + ocol + 8];
        __syncthreads();
    }
}

// ---------------------------------------------------------------------------
// attn^T[e][d] = (1/N) * sum_{t in chunk, n} v[e,n] * k[d,n] (exact integers),
// stored as exact hi/lo bf16 split. 4 waves split the 64 s-steps, LDS reduce.
// ---------------------------------------------------------------------------
__global__ __launch_bounds__(256) void k_attn(const bf16_t* __restrict__ vc,
                                              const bf16_t* __restrict__ kc,
                                              bf16_t* __restrict__ ahi,
                                              bf16_t* __restrict__ alo)
{
    __shared__ float red[3][64][20];            // pad 20: 16B-aligned rows
    const int fid = blockIdx.x;                 // ((nc*16+b)*8+h)
    const int h = fid & 7, b = (fid >> 3) & 15, nc = fid >> 7;
    const int tid = threadIdx.x, w = tid >> 6, l = tid & 63, lq = l >> 4, lr = l & 15;
    f32x4 acc[4];
#pragma unroll
    for (int i = 0; i < 4; i++) acc[i] = (f32x4){0.f, 0.f, 0.f, 0.f};
    for (int ss = 0; ss < 16; ss++) {
        int s = w * 16 + ss;
        int t = nc * 2 + (s >> 5);
        int n0 = (s & 31) * 32;
        size_t rb = ((size_t)(t * B_ + b) * C_ + h * D_ + lr) * V_ + n0 + lq * 8;
        bf16x8 a0 = *(const bf16x8*)&vc[rb];
        bf16x8 a1 = *(const bf16x8*)&vc[rb + (size_t)16 * V_];
        bf16x8 b0 = *(const bf16x8*)&kc[rb];
        bf16x8 b1 = *(const bf16x8*)&kc[rb + (size_t)16 * V_];
        acc[0] = MFMA(a0, b0, acc[0], 0, 0, 0);
        acc[1] = MFMA(a0, b1, acc[1], 0, 0, 0);
        acc[2] = MFMA(a1, b0, acc[2], 0, 0, 0);
        acc[3] = MFMA(a1, b1, acc[3], 0, 0, 0);
    }
    if (w) {
#pragma unroll
        for (int st = 0; st < 4; st++)
            *(f32x4*)&red[w - 1][l][st * 4] = acc[st];
    }
    __syncthreads();
    if (w == 0) {
#pragma unroll
        for (int st = 0; st < 4; st++)
#pragma unroll
            for (int i = 0; i < 3; i++)
                acc[st] += *(const f32x4*)&red[i][l][st * 4];

        size_t ob = (size_t)fid * 1024;
#pragma unroll
        for (int st = 0; st < 4; st++) {
            int ei = st >> 1, di = st & 1;
#pragma unroll
            for (int r = 0; r < 4; r++) {
                int e = ei * 16 + lq * 4 + r;
                int d = di * 16 + lr;
                float val = acc[st][r] * (1.0f / 1024.0f);   // exact dyadic
                bf16_t hi = (bf16_t)val;
                float lo = val - (float)hi;                  // exact residual
                ahi[ob + e * 32 + d] = hi;
                alo[ob + e * 32 + d] = (bf16_t)lo;
            }
        }
    }
}

// ---------------------------------------------------------------------------
// y2 = q . attn (exact hi/lo double-MFMA), fused attn_lif (vth=0.5, exact)
// -> spikes y3T v-major [T,B,V,C]
// ---------------------------------------------------------------------------
__global__ __launch_bounds__(256) void k_attn_out(const bf16_t* __restrict__ qT,
                                                  const bf16_t* __restrict__ ahi,
                                                  const bf16_t* __restrict__ alo,
                                                  bf16_t* __restrict__ y3T)
{
    const int tid = threadIdx.x, w = tid >> 6, l = tid & 63, lq = l >> 4, lr = l & 15;
    const int n0 = blockIdx.x * 64 + (w >> 1) * 32;
    const int h = blockIdx.y * 2 + (w & 1);
    const int b = blockIdx.z;
    float mem[4][4];
#pragma unroll
    for (int st = 0; st < 4; st++)
#pragma unroll
        for (int r = 0; r < 4; r++) mem[st][r] = 0.0f;

    for (int t = 0; t < T_; t++) {
        int nc = t >> 1;
        const bf16_t* qp = qT + ((size_t)(t * B_ + b) * V_ + n0 + lr) * C_ + h * D_ + lq * 8;
        bf16x8 a0 = *(const bf16x8*)qp;
        bf16x8 a1 = *(const bf16x8*)(qp + 16 * C_);
        size_t ab = ((size_t)(nc * B_ + b) * H_ + h) * 1024;
        bf16x8 bh0 = *(const bf16x8*)&ahi[ab + lr * 32 + lq * 8];
        bf16x8 bh1 = *(const bf16x8*)&ahi[ab + (16 + lr) * 32 + lq * 8];
        bf16x8 bl0 = *(const bf16x8*)&alo[ab + lr * 32 + lq * 8];
        bf16x8 bl1 = *(const bf16x8*)&alo[ab + (16 + lr) * 32 + lq * 8];
#pragma unroll
        for (int st = 0; st < 4; st++) {
            int mi = st >> 1, ni = st & 1;
            f32x4 z = (f32x4){0.f, 0.f, 0.f, 0.f};
            z = MFMA(mi ? a1 : a0, ni ? bh1 : bh0, z, 0, 0, 0);
            z = MFMA(mi ? a1 : a0, ni ? bl1 : bl0, z, 0, 0, 0);
#pragma unroll
            for (int r = 0; r < 4; r++) {
                int n = n0 + mi * 16 + lq * 4 + r;
                int e = ni * 16 + lr;
                float mm = mem[st][r];
                mm = mm + (z[r] - mm) * 0.5f;
                float s = (mm >= 0.5f) ? 1.0f : 0.0f;
                y3T[((size_t)(t * B_ + b) * V_ + n) * C_ + h * D_ + e] = (bf16_t)s;
                mem[st][r] = (s != 0.0f) ? 0.0f : mm;
            }
        }
    }
}

// ---------------------------------------------------------------------------
// proj GEMM (triple split, round-1 body) + bias + BN + identity -> f32.
// Round-5 epilogue: y through f32 LDS tile; x read and out0 store as float4
// (4-lane groups cover 256B contiguous) instead of 64 scalar loads+stores.
// ---------------------------------------------------------------------------
__global__ __launch_bounds__(256, 2) void k_proj(const bf16_t* __restrict__ Wsp,
                                                 const float* __restrict__ pb,
                                                 const float* __restrict__ bnp,
                                                 const bf16_t* __restrict__ y3T,
                                                 const float* __restrict__ x,
                                                 float* __restrict__ out0)
{
    __shared__ bf16_t Wl[3][64 * 40];
    __shared__ bf16_t Xl[8][64 * 40];
    __shared__ float bsc[64], bmn[64], bbt[64], bbi[64];
    const int v0 = blockIdx.x * 64, o0 = blockIdx.y * 64, b = blockIdx.z;
    const int tid = threadIdx.x;
    const int w = tid >> 6, l = tid & 63, lq = l >> 4, lr = l & 15;
    const int msub = (w >> 1) * 32, nsub = (w & 1) * 32;

    if (tid < 64) {
        int o = o0 + tid;
        float g = bnp[o], be = bnp[C_ + o];
        float mn = bnp[2 * C_ + o], vr2 = bnp[3 * C_ + o];
        bsc[tid] = g * (1.0f / sqrtf(vr2 + 1e-5f));
        bmn[tid] = mn; bbt[tid] = be; bbi[tid] = pb[o];
    }

    f32x4 acc[8][4];
#pragma unroll
    for (int t = 0; t < 8; t++)
#pragma unroll
        for (int i = 0; i < 4; i++) acc[t][i] = (f32x4){0.f, 0.f, 0.f, 0.f};

    for (int kq = 0; kq < 8; kq++) {
        __syncthreads();
#pragma unroll
        for (int i = 0; i < 3; i++) {
            int ch = tid + i * 256;
            int lvl = ch >> 8, rem = ch & 255;
            int row = rem >> 2, col8 = (rem & 3) * 8;
            *(bf16x8*)&Wl[lvl][row * 40 + col8] =
                *(const bf16x8*)&Wsp[lvl * 65536 + (o0 + row) * 256 + kq * 32 + col8];
        }
#pragma unroll
        for (int i = 0; i < 8; i++) {
            int ch = tid + i * 256;
            int tt = ch >> 8, rem = ch & 255;
            int row = rem >> 2, col8 = (rem & 3) * 8;
            *(bf16x8*)&Xl[tt][row * 40 + col8] =
                *(const bf16x8*)&y3T[((size_t)(tt * B_ + b) * V_ + v0 + row) * C_ + kq * 32 + col8];
        }
        __syncthreads();

        bf16x8 aw0[3], aw1[3];
#pragma unroll
        for (int lvl = 0; lvl < 3; lvl++) {
            aw0[lvl] = *(const bf16x8*)&Wl[lvl][(msub + lr) * 40 + lq * 8];
            aw1[lvl] = *(const bf16x8*)&Wl[lvl][(msub + 16 + lr) * 40 + lq * 8];
        }
#pragma unroll
        for (int t = 0; t < 8; t++) {
            bf16x8 b0 = *(const bf16x8*)&Xl[t][(nsub + lr) * 40 + lq * 8];
            bf16x8 b1 = *(const bf16x8*)&Xl[t][(nsub + 16 + lr) * 40 + lq * 8];
#pragma unroll
            for (int lvl = 0; lvl < 3; lvl++) {
                acc[t][0] = MFMA(aw0[lvl], b0, acc[t][0], 0, 0, 0);
                acc[t][1] = MFMA(aw0[lvl], b1, acc[t][1], 0, 0, 0);
                acc[t][2] = MFMA(aw1[lvl], b0, acc[t][2], 0, 0, 0);
                acc[t][3] = MFMA(aw1[lvl], b1, acc[t][3], 0, 0, 0);
            }
        }
    }

    // epilogue: bias+BN through f32 LDS tile, float4 x-read + float4 store
    __syncthreads();                      // all waves done reading Xl
    float* tf = (float*)Xl;               // 64 x 68 f32 tile (17 KiB), aliases Xl
    const int orow = tid >> 2, ocol = (tid & 3) * 16;
#pragma unroll
    for (int t = 0; t < 8; t++) {
#pragma unroll
        for (int st = 0; st < 4; st++) {
            int mi = st >> 1, ni = st & 1;
#pragma unroll
            for (int r = 0; r < 4; r++) {
                int m = msub + mi * 16 + lq * 4 + r;
                int n = nsub + ni * 16 + lr;
                float y = acc[t][st][r] + bbi[m];
                y = (y - bmn[m]) * bsc[m] + bbt[m];
                tf[m * 68 + n] = y;
            }
        }
        __syncthreads();
        size_t rowbase = ((size_t)(t * B_ + b) * C_ + (o0 + orow)) * V_ + v0 + ocol;
#pragma unroll
        for (int q = 0; q < 4; q++) {
            float4 xv = *(const float4*)&x[rowbase + q * 4];
            float4 yv = *(const float4*)&tf[orow * 68 + ocol + q * 4];
            yv.x += xv.x; yv.y += xv.y; yv.z += xv.z; yv.w += xv.w;
            *(float4*)&out0[rowbase + q * 4] = yv;
        }
        __syncthreads();
    }
}

// ---------------------------------------------------------------------------
// output 1: v spikes [T,B,C,V] -> f32 [T,B,H,N,D]
// ---------------------------------------------------------------------------
__global__ __launch_bounds__(256) void k_vout(const bf16_t* __restrict__ vc,
                                              float* __restrict__ out1)
{
    __shared__ bf16_t tl[32 * 136];
    const int n0 = blockIdx.x * 128;
    const int f = blockIdx.y;                 // (t*16+b)*8+h
    const int tb = f >> 3, h = f & 7;
    const int tid = threadIdx.x;
    {
        int d = tid >> 3, nn = (tid & 7) * 16;
        const bf16_t* vp = vc + ((size_t)tb * C_ + h * D_ + d) * V_ + n0 + nn;
        *(bf16x8*)&tl[d * 136 + nn]     = *(const bf16x8*)vp;
        *(bf16x8*)&tl[d * 136 + nn + 8] = *(const bf16x8*)(vp + 8);
    }
    __syncthreads();
    {
        int n = tid >> 1, d16 = (tid & 1) * 16;
        float* op = out1 + (size_t)f * (V_ * D_) + (size_t)(n0 + n) * D_ + d16;
#pragma unroll
        for (int q = 0; q < 4; q++) {
            float4 o;
            o.x = (float)tl[(d16 + q * 4 + 0) * 136 + n];
            o.y = (float)tl[(d16 + q * 4 + 1) * 136 + n];
            o.z = (float)tl[(d16 + q * 4 + 2) * 136 + n];
            o.w = (float)tl[(d16 + q * 4 + 3) * 136 + n];
            *(float4*)(op + q * 4) = o;
        }
    }
}

// ---------------------------------------------------------------------------
extern "C" void kernel_launch(void* const* d_in, const int* in_sizes, int n_in,
                              void* d_out, int out_size, void* d_ws, size_t ws_size,
                              hipStream_t stream)
{
    const float* x    = (const float*)d_in[0];
    const float* q_w  = (const float*)d_in[1];
    const float* k_w  = (const float*)d_in[2];
    const float* v_w  = (const float*)d_in[3];
    const float* pw   = (const float*)d_in[4];
    const float* pb   = (const float*)d_in[5];
    const float* bn_q = (const float*)d_in[6];
    const float* bn_k = (const float*)d_in[7];
    const float* bn_v = (const float*)d_in[8];
    const float* bn_p = (const float*)d_in[9];

    char* ws = (char*)d_ws;
    bf16_t* xsT  = (bf16_t*)(ws);                                 // 64 MiB (reused as y3T)
    bf16_t* vc   = (bf16_t*)(ws + ((size_t)64 << 20));            // 64 MiB
    bf16_t* ahi  = (bf16_t*)(ws + ((size_t)128 << 20));           // 1 MiB
    bf16_t* alo  = (bf16_t*)(ws + ((size_t)129 << 20));           // 1 MiB
    bf16_t* wspq = (bf16_t*)(ws + ((size_t)130 << 20));           // 4 x 384 KiB
    bf16_t* wspk = wspq + 3 * 65536;
    bf16_t* wspv = wspk + 3 * 65536;
    bf16_t* wspp = wspv + 3 * 65536;
    bf16_t* y3T  = xsT;                                           // reuse after v-branch

    float* outf = (float*)d_out;
    bf16_t* qT = (bf16_t*)d_out;                                  // scratch in out0 half
    bf16_t* kc = (bf16_t*)((char*)d_out + ((size_t)64 << 20));    // scratch in out0 half

    k0_split4  <<<dim3(256),        256, 0, stream>>>(q_w, k_w, v_w, pw, wspq);
    k1_lif_tr  <<<dim3(16, 4, 16),  256, 0, stream>>>(x, xsT);
    k_branch<1><<<dim3(16, 4, 16),  256, 0, stream>>>(wspq, bn_q, xsT, qT, 1.0f);
    k_branch<0><<<dim3(16, 4, 16),  256, 0, stream>>>(wspk, bn_k, xsT, kc, 1.0f);
    k_branch<0><<<dim3(16, 4, 16),  256, 0, stream>>>(wspv, bn_v, xsT, vc, 1.0f);
    k_attn     <<<dim3(512),        256, 0, stream>>>(vc, kc, ahi, alo);
    k_attn_out <<<dim3(16, 4, 16),  256, 0, stream>>>(qT, ahi, alo, y3T);
    k_proj     <<<dim3(16, 4, 16),  256, 0, stream>>>(wspp, pb, bn_p, y3T, x, outf);
    k_vout     <<<dim3(8, 1024),    256, 0, stream>>>(vc, outf + (size_t)33554432);
}